// Round 4
// baseline (3012.906 us; speedup 1.0000x reference)
//
#include <hip/hip_runtime.h>
#include <stdint.h>

typedef unsigned short ushort_t;

#define NN    2048
#define DIMC  256
#define H1    1030
#define MD    64
#define NROWS 8192

__device__ __forceinline__ float bfu2f(ushort_t u){ union{unsigned u; float f;} v; v.u = ((unsigned)u)<<16; return v.f; }
__device__ __forceinline__ ushort_t f2bfu(float f){ union{float f; unsigned u;} v; v.f=f; unsigned r = (v.u + 0x7FFFu + ((v.u>>16)&1u))>>16; return (ushort_t)r; }
__device__ __forceinline__ float siluf(float x){ return x / (1.0f + __expf(-x)); }

__global__ void mask_kernel(const int* __restrict__ mask, float* __restrict__ out_mask){
    int t = blockIdx.x*256 + threadIdx.x;
    if (t < NROWS) out_mask[t] = mask[t] ? 1.0f : 0.0f;
}

// ---------------- adj scan: bool->f32 passthrough + neighbor extraction + pair emission ----------------
// Selection semantics (VALID_RADIUS=0): self (ranking -1) + adjacency-non-self (ranking 0),
// truncated to the 15 lowest-index adjacency neighbors (top_k K=16, stable ties).
// Contribution requires mask[i] (self) and mask[i]&mask[j] (neighbor).
__global__ void adj_kernel(const int* __restrict__ adj, const int* __restrict__ mask,
                           float* __restrict__ out_adj, int* __restrict__ pairs,
                           int* __restrict__ counter)
{
    const int w = threadIdx.x >> 6, lane = threadIdx.x & 63;
    const int row = blockIdx.x*4 + w;
    const int b = row >> 11, i = row & (NN-1);
    __shared__ int nbrs[4][15];
    int total = 0;
    const size_t rbase = (size_t)row * NN;
    for (int c = 0; c < NN/64; c++) {
        int j = c*64 + lane;
        int v = adj[rbase + j];
        out_adj[rbase + j] = v ? 1.0f : 0.0f;
        bool pred = (v != 0) && (j != i);
        unsigned long long bm = __ballot(pred);
        if (pred) {
            int slot = total + __popcll(bm & ((1ull<<lane)-1ull));
            if (slot < 15) nbrs[w][slot] = j;
        }
        total += __popcll(bm);
    }
    int cnt = total < 15 ? total : 15;
    if (mask[row] != 0) {
        int jl = (lane < cnt) ? nbrs[w][lane] : 0;
        bool ok = (lane < cnt) && (mask[b*NN + jl] != 0);
        unsigned long long bm = __ballot(ok);
        int npair = 1 + __popcll(bm);
        int basep = 0;
        if (lane == 0) basep = atomicAdd(counter, npair);
        basep = __shfl(basep, 0);
        if (lane == 0) pairs[basep] = (row << 16) | i;      // self pair
        if (ok) {
            int pos = basep + 1 + __popcll(bm & ((1ull<<lane)-1ull));
            pairs[pos] = (row << 16) | jl;
        }
    }
}

// ---------------- P/Q precompute (scalar fp32): P = emb @ eW1[0:256], Q = emb @ eW1[256:512] ----
__global__ void gemm_pq(const float* __restrict__ emb, const float* __restrict__ eW1,
                        ushort_t* __restrict__ Pb, ushort_t* __restrict__ Qb)
{
    size_t t = (size_t)blockIdx.x*256 + threadIdx.x;
    const size_t PER = (size_t)NROWS * H1;
    if (t >= 2*PER) return;
    int which = (int)(t / PER);
    size_t rem = t - (size_t)which*PER;
    int r = (int)(rem / H1), c = (int)(rem % H1);
    const float* a = emb + (size_t)r*DIMC;
    const float* bcol = eW1 + (size_t)(which*256)*H1 + c;
    float acc = 0.f;
#pragma unroll 4
    for (int k = 0; k < DIMC; k++) acc += a[k] * bcol[(size_t)k*H1];
    (which ? Qb : Pb)[rem] = f2bfu(acc);
}

// ---------------- edge MLP per pair (scalar fp32) ----------------
__global__ __launch_bounds__(256)
void edge_simple(const int* __restrict__ pairs, const int* __restrict__ counter,
                 const ushort_t* __restrict__ P, const ushort_t* __restrict__ Q,
                 const float* __restrict__ coors, const float* __restrict__ feat,
                 const float* __restrict__ eW1, const float* __restrict__ eb1,
                 const float* __restrict__ eW2, const float* __restrict__ eb2,
                 float* __restrict__ macc)
{
    const int np = counter[0];
    const int ip = blockIdx.x;
    if (ip >= np) return;
    __shared__ float hsh[H1];
    __shared__ float red[4][MD];
    const int e = pairs[ip];
    const int row = e >> 16, j = e & 0xFFFF;
    const int jr = ((row >> 11) << 11) + j;
    const float dx = coors[(size_t)row*3+0] - coors[(size_t)jr*3+0];
    const float dy = coors[(size_t)row*3+1] - coors[(size_t)jr*3+1];
    const float dz = coors[(size_t)row*3+2] - coors[(size_t)jr*3+2];
    const float d  = dx*dx + dy*dy + dz*dz;
    const size_t fo = ((size_t)row*NN + j)*2;
    const float f0 = feat[fo], f1 = feat[fo+1];
    const float* w512 = eW1 + (size_t)512*H1;
    const float* w513 = eW1 + (size_t)513*H1;
    const float* w514 = eW1 + (size_t)514*H1;
    for (int c = threadIdx.x; c < H1; c += 256) {
        float h = bfu2f(P[(size_t)row*H1 + c]) + bfu2f(Q[(size_t)jr*H1 + c])
                + d*w512[c] + f0*w513[c] + f1*w514[c] + eb1[c];
        hsh[c] = siluf(h);
    }
    __syncthreads();
    const int col = threadIdx.x & 63, grp = threadIdx.x >> 6;
    float acc = 0.f;
    for (int c = grp; c < H1; c += 4)
        acc += hsh[c] * eW2[(size_t)c*MD + col];
    red[grp][col] = acc;
    __syncthreads();
    if (grp == 0) {
        float s = red[0][col] + red[1][col] + red[2][col] + red[3][col];
        float m = siluf(s + eb2[col]);
        atomicAdd(&macc[(size_t)row*MD + col], m);
    }
}

// ---------------- node MLP layer 1 (scalar fp32): hidden = silu([emb||m_i] @ nW1 + nb1) ----
__global__ void node1_kernel(const float* __restrict__ emb, const float* __restrict__ macc,
                             const float* __restrict__ nW1, const float* __restrict__ nb1,
                             float* __restrict__ hidden)
{
    size_t t = (size_t)blockIdx.x*256 + threadIdx.x;
    if (t >= (size_t)NROWS*512) return;
    int r = (int)(t / 512), c = (int)(t % 512);
    const float* a = emb + (size_t)r*DIMC;
    const float* m = macc + (size_t)r*MD;
    float acc = nb1[c];
#pragma unroll 4
    for (int k = 0; k < DIMC; k++) acc += a[k] * nW1[(size_t)k*512 + c];
#pragma unroll 4
    for (int k = 0; k < MD; k++)   acc += m[k] * nW1[(size_t)(DIMC+k)*512 + c];
    hidden[t] = siluf(acc);
}

// ---------------- node MLP layer 2 (scalar fp32): out = hidden @ nW2 + nb2 + emb (f32 out) ----
__global__ void node2_kernel(const float* __restrict__ hidden, const float* __restrict__ nW2,
                             const float* __restrict__ nb2, const float* __restrict__ emb,
                             float* __restrict__ out_node)
{
    size_t t = (size_t)blockIdx.x*256 + threadIdx.x;
    if (t >= (size_t)NROWS*DIMC) return;
    int r = (int)(t / DIMC), c = (int)(t % DIMC);
    const float* a = hidden + (size_t)r*512;
    float acc = nb2[c];
#pragma unroll 4
    for (int k = 0; k < 512; k++) acc += a[k] * nW2[(size_t)k*DIMC + c];
    out_node[t] = acc + emb[t];
}

extern "C" void kernel_launch(void* const* d_in, const int* in_sizes, int n_in,
                              void* d_out, int out_size, void* d_ws, size_t ws_size,
                              hipStream_t stream)
{
    const float* emb   = (const float*)d_in[0];
    const float* coors = (const float*)d_in[1];
    const int*   adj   = (const int*)d_in[2];
    const float* feat  = (const float*)d_in[3];
    const int*   mask  = (const int*)d_in[4];
    const float* eW1   = (const float*)d_in[5];
    const float* eb1   = (const float*)d_in[6];
    const float* eW2   = (const float*)d_in[7];
    const float* eb2   = (const float*)d_in[8];
    const float* nW1   = (const float*)d_in[9];
    const float* nb1   = (const float*)d_in[10];
    const float* nW2   = (const float*)d_in[11];
    const float* nb2   = (const float*)d_in[12];

    float* out       = (float*)d_out;
    float* out_node  = out;               // [4,2048,256]   2,097,152
    float* out_coors = out + 2097152;     // [4,2048,3]        24,576
    float* out_adj   = out + 2121728;     // [4,2048,2048] 16,777,216
    float* out_feat  = out + 18898944;    // [4,2048,2048,2] 33,554,432
    float* out_mask  = out + 52453376;    // [4,2048]           8,192

    char* ws = (char*)d_ws;
    int*      counter = (int*)(ws + 0);            // 256 B
    float*    macc    = (float*)(ws + 256);        // 8192x64 f32 -> ends 2,097,408
    int*      pairs   = (int*)(ws + 2097408);      // 131072 ints -> ends 2,621,696
    ushort_t* Pbuf    = (ushort_t*)(ws + 2621696); // 8192x1030 bf16 -> ends 19,497,216
    ushort_t* Qbuf    = (ushort_t*)(ws + 19497216);// 8192x1030 bf16 -> ends 36,372,736
    float*    hidden  = (float*)(ws + 2621696);    // 8192x512 f32, REUSES Pbuf region (dead by then)

    hipMemsetAsync(counter, 0, 256, stream);
    hipMemsetAsync(macc, 0, (size_t)NROWS*MD*sizeof(float), stream);

    hipMemcpyAsync(out_coors, coors, (size_t)24576*sizeof(float), hipMemcpyDeviceToDevice, stream);
    hipMemcpyAsync(out_feat,  feat,  (size_t)33554432*sizeof(float), hipMemcpyDeviceToDevice, stream);

    mask_kernel<<<(NROWS + 255)/256, 256, 0, stream>>>(mask, out_mask);
    adj_kernel<<<NROWS/4, 256, 0, stream>>>(adj, mask, out_adj, pairs, counter);

    {
        size_t tot = 2ull * NROWS * H1;
        gemm_pq<<<(unsigned)((tot + 255)/256), 256, 0, stream>>>(emb, eW1, Pbuf, Qbuf);
    }

    edge_simple<<<131072, 256, 0, stream>>>(pairs, counter, Pbuf, Qbuf, coors, feat,
                                            eW1, eb1, eW2, eb2, macc);

    node1_kernel<<<(NROWS*512 + 255)/256, 256, 0, stream>>>(emb, macc, nW1, nb1, hidden);
    node2_kernel<<<(NROWS*DIMC + 255)/256, 256, 0, stream>>>(hidden, nW2, nb2, emb, out_node);
}